// Round 13
// baseline (86.732 us; speedup 1.0000x reference)
//
#include <hip/hip_runtime.h>
#include <math.h>

#define NHEAD 8
#define HEAD_DIM 32
#define IMG_H 32
#define IMG_W 40
#define NPIX (IMG_H*IMG_W)
#define CMAX 160
#define CPW (CMAX/2)     // 80 candidates per wave (2 waves/block)
#define FEAT (NHEAD*HEAD_DIM)

// ===== Geometry: LOCKED bit-exact numpy-fp32 emulation =====
// R27: register-LU (explicit scalars + pivot selects, arithmetic 1:1 with
// numpy chain) -> fusable without scratch demotion. PASSED, absmax 2^-10.

__device__ __forceinline__ void np_inv3x3_reg(const float* __restrict__ M, float inv[3][3]) {
#pragma clang fp contract(off)
    float a00=M[0], a01=M[1], a02=M[2];
    float a10=M[3], a11=M[4], a12=M[5];
    float a20=M[6], a21=M[7], a22=M[8];

    // ---- kk=0: pivot search (strictly-greater update, as numpy) ----
    const float c0 = fabsf(a00), c1 = fabsf(a10), c2 = fabsf(a20);
    const bool s1 = c1 > c0;
    const float cm = s1 ? c1 : c0;
    const bool s2 = c2 > cm;
    const bool q1 = s1 && !s2;      // pivot row 1
    const bool q2 = s2;             // pivot row 2 (q1,q2 mutually exclusive)
    {   // full row swap 0 <-> p0
        const float n0 = q2 ? a20 : (q1 ? a10 : a00);
        const float n1 = q2 ? a21 : (q1 ? a11 : a01);
        const float n2 = q2 ? a22 : (q1 ? a12 : a02);
        const float m0 = q1 ? a00 : a10, m1 = q1 ? a01 : a11, m2 = q1 ? a02 : a12;
        const float r0 = q2 ? a00 : a20, r1 = q2 ? a01 : a21, r2 = q2 ? a02 : a22;
        a00=n0; a01=n1; a02=n2;
        a10=m0; a11=m1; a12=m2;
        a20=r0; a21=r1; a22=r2;
    }
    const float rp0 = 1.0f / a00;
    a10 = a10 * rp0;
    a20 = a20 * rp0;
    a11 = a11 - a10*a01;
    a12 = a12 - a10*a02;
    a21 = a21 - a20*a01;
    a22 = a22 - a20*a02;

    // ---- kk=1: pivot search over rows 1,2 ----
    const bool sB = fabsf(a21) > fabsf(a11);
    {   // full row swap 1 <-> 2 (includes factored column 0, as numpy)
        const float t0 = sB ? a20 : a10, t1 = sB ? a21 : a11, t2 = sB ? a22 : a12;
        const float u0 = sB ? a10 : a20, u1 = sB ? a11 : a21, u2 = sB ? a12 : a22;
        a10=t0; a11=t1; a12=t2;
        a20=u0; a21=u1; a22=u2;
    }
    const float rp1 = 1.0f / a11;
    a21 = a21 * rp1;
    a22 = a22 - a21*a12;
    // kk=2: pivot is row 2, no swap, no elimination.

    // ---- solve A x = e_col for col=0,1,2 (constant-trip, unrolled) ----
    #pragma unroll
    for (int col = 0; col < 3; col++) {
        float b0 = (col==0) ? 1.0f : 0.0f;
        float b1 = (col==1) ? 1.0f : 0.0f;
        float b2 = (col==2) ? 1.0f : 0.0f;
        {   // apply piv[0]
            const float w0 = q2 ? b2 : (q1 ? b1 : b0);
            const float w1 = q1 ? b0 : b1;
            const float w2 = q2 ? b0 : b2;
            b0=w0; b1=w1; b2=w2;
        }
        {   // apply piv[1]
            const float x1 = sB ? b2 : b1;
            const float x2 = sB ? b1 : b2;
            b1=x1; b2=x2;
        }
        // forward substitution (i=1:kk=0; i=2:kk=0,1)
        b1 = b1 - a10*b0;
        b2 = b2 - a20*b0;
        b2 = b2 - a21*b1;
        // back substitution (kk=2: i=0,1; kk=1: i=0; kk=0)
        b2 = b2 / a22;
        b0 = b0 - a02*b2;
        b1 = b1 - a12*b2;
        b1 = b1 / a11;
        b0 = b0 - a01*b1;
        b0 = b0 / a00;
        inv[0][col]=b0; inv[1][col]=b1; inv[2][col]=b2;
    }
}

__device__ __forceinline__ void mm3_chain(const float A[3][3], const float B[3][3], float C[3][3]) {
#pragma clang fp contract(off)
    for (int i=0;i<3;i++)
        for (int j=0;j<3;j++) {
            float acc = A[i][0]*B[0][j];
            acc = acc + A[i][1]*B[1][j];
            acc = acc + A[i][2]*B[2][j];
            C[i][j] = acc;
        }
}
__device__ __forceinline__ void mm3_fma(const float A[3][3], const float B[3][3], float C[3][3]) {
#pragma clang fp contract(off)
    for (int i=0;i<3;i++)
        for (int j=0;j<3;j++) {
            float acc = A[i][0]*B[0][j];
            acc = __builtin_fmaf(A[i][1], B[1][j], acc);
            acc = __builtin_fmaf(A[i][2], B[2][j], acc);
            C[i][j] = acc;
        }
}
__device__ __forceinline__ float einsum_row(const float Fi[3], float x, float y) {
#pragma clang fp contract(off)
    float acc = Fi[0]*x;
    acc = acc + Fi[1]*y;
    acc = acc + Fi[2]*1.0f;
    return acc;
}

// ===== R34: R33 coalesced gather + 128-thread blocks (no straggler round) =====
// R33 (83.4 us) proved the wave-uniform 1024-B gather. Remaining lever:
// 256-thread blocks need 5 blocks/CU but fit only 4 at VGPR 65-128 ->
// serialized 5th round at 1/4 occupancy (R32's test of this was confounded
// by the divergent layout). 128-thread/2-wave blocks need only 10 waves/CU
// = 2.5 waves/SIMD -> whole grid co-resident in ONE round for any VGPR
// <= ~200, no launch_bounds cap needed (R30/R31 spill lesson). CPW=80,
// #pragma unroll 8 bounds in-flight VGPR. Combine shrinks to 2 waves.

__global__ __launch_bounds__(128) void one2many_fused(
    const float* __restrict__ q, const float* __restrict__ k, const float* __restrict__ v,
    const float* __restrict__ K0, const float* __restrict__ K1,
    const float* __restrict__ R, const float* __restrict__ t,
    float* __restrict__ out)
{
#pragma clang fp contract(off)
    __shared__ int s_cand[CMAX];
    __shared__ int s_cnt;
    __shared__ float s_ax[128], s_ay[128], s_az[128], s_aw[128], s_ps[128];

    const int bx  = blockIdx.x;
    const int l   = (bx >> 3) + (bx & 7) * 160;   // XCD-contiguous bijection on [0,1280)
    const int tid = threadIdx.x;

    if (tid == 0) s_cnt = 0;

    const int w    = tid >> 6;          // wave index 0..1
    const int lane = tid & 63;          // lane -> (head = lane>>3, dims = (lane&7)*4)

    // q: each lane holds its (head,dims) slice; wave covers the full row.
    const float4 q4 = *(const float4*)(q + l*FEAT + (lane << 2));

    // ---- geometry: locked bit-exact chain, all threads, register-resident ----
    float slope, icpt; bool mode;
    {
        float i0[3][3], i1[3][3], A[3][3], B[3][3], T1[3][3], T2[3][3], Fm[3][3], Rm[3][3];
        np_inv3x3_reg(K0, i0);
        np_inv3x3_reg(K1, i1);
        for (int i=0;i<3;i++)
            for (int j=0;j<3;j++) { A[i][j] = i1[j][i]; Rm[i][j] = R[i*3+j]; }
        const float t0=t[0], t1=t[1], t2=t[2];
        B[0][0]=0.f;  B[0][1]=-t2;  B[0][2]=t1;
        B[1][0]=t2;   B[1][1]=0.f;  B[1][2]=-t0;
        B[2][0]=-t1;  B[2][1]=t0;   B[2][2]=0.f;
        mm3_chain(A,B,T1);      // noblas (swapaxes view)
        mm3_chain(T1,Rm,T2);    // T1 @ I
        mm3_fma(T2,i0,Fm);      // sgemm FMA
        const float xl = (float)(l % IMG_W);
        const float yl = (float)(l / IMG_W);
        const float la = einsum_row(Fm[0], xl, yl);
        const float lb = einsum_row(Fm[1], xl, yl);
        const float lc = einsum_row(Fm[2], xl, yl);
        mode = fabsf(lb) > fabsf(la);
        const float denom = mode ? lb : la;
        slope = (mode ? -la : -lb) / denom;
        icpt  = (-lc) / denom;
    }

    __syncthreads();   // s_cnt=0 visible

    // ---- candidate collection: identical fp32 band test ----
    for (int m = tid; m < NPIX; m += 128) {
        const float xm = (float)(m % IMG_W), ym = (float)(m / IMG_W);
        const float tin  = mode ? xm : ym;
        const float tchk = mode ? ym : xm;
        const float mu = slope * tin;
        const float cc = mu + icpt;
        const float hi = cc + 2.0f;
        const float lo = cc - 2.0f;
        if ((tchk < hi) && (tchk > lo) && m != 0) {
            int pos = atomicAdd(&s_cnt, 1);
            if (pos < CMAX) s_cand[pos] = m;
        }
    }
    __syncthreads();
    const int nc = min(s_cnt, CMAX);

    const float* kl = k + (lane << 2);
    const float* vl = v + (lane << 2);

    // ---- single-pass QK+softmax+AV; one wave-uniform candidate per iter ----
    float ax = 0.f, ay = 0.f, az = 0.f, aw = 0.f, ps = 0.f;
    const int cbase = w * CPW;
    #pragma unroll 8
    for (int i = 0; i < CPW; i++) {
        const int ci   = cbase + i;
        const bool live = (ci < nc);
        const int row  = __builtin_amdgcn_readfirstlane(s_cand[live ? ci : 0]);
        const size_t off = (size_t)row * FEAT;
        const float4 kk = *(const float4*)(kl + off);   // 64 lanes -> contiguous 1024 B
        const float4 vv = *(const float4*)(vl + off);   // 64 lanes -> contiguous 1024 B
        float p = q4.x*kk.x;
        p = __builtin_fmaf(q4.y, kk.y, p);
        p = __builtin_fmaf(q4.z, kk.z, p);
        p = __builtin_fmaf(q4.w, kk.w, p);
        p += __shfl_xor(p, 1);
        p += __shfl_xor(p, 2);
        p += __shfl_xor(p, 4);              // full head-dot in all 8 lanes of the group
        const float e = live ? __expf(p * 0.17677669529663687f) : 0.0f;
        ps += e;
        ax = __builtin_fmaf(e, vv.x, ax);
        ay = __builtin_fmaf(e, vv.y, ay);
        az = __builtin_fmaf(e, vv.z, az);
        aw = __builtin_fmaf(e, vv.w, aw);
    }

    // ---- cross-wave combine (each thread owns (head,dims) partials) ----
    s_ax[tid] = ax; s_ay[tid] = ay; s_az[tid] = az; s_aw[tid] = aw; s_ps[tid] = ps;
    __syncthreads();

    if (tid < 64) {
        const float fax = s_ax[tid] + s_ax[tid+64];
        const float fay = s_ay[tid] + s_ay[tid+64];
        const float faz = s_az[tid] + s_az[tid+64];
        const float faw = s_aw[tid] + s_aw[tid+64];
        const float fps = s_ps[tid] + s_ps[tid+64];
        float4 r;
        if (nc > 0) { r.x = fax/fps; r.y = fay/fps; r.z = faz/fps; r.w = faw/fps; }
        else        { r.x = r.y = r.z = r.w = 0.0f; }
        *(float4*)(out + l*FEAT + (tid << 2)) = r;   // 64 lanes -> contiguous 1024 B
    }
}

extern "C" void kernel_launch(void* const* d_in, const int* in_sizes, int n_in,
                              void* d_out, int out_size, void* d_ws, size_t ws_size,
                              hipStream_t stream) {
    const float* q  = (const float*)d_in[0];
    const float* k  = (const float*)d_in[1];
    const float* v  = (const float*)d_in[2];
    const float* K0 = (const float*)d_in[3];
    const float* K1 = (const float*)d_in[4];
    const float* R  = (const float*)d_in[5];
    const float* t  = (const float*)d_in[6];
    float* out = (float*)d_out;
    (void)d_ws; (void)ws_size;
    one2many_fused<<<NPIX, 128, 0, stream>>>(q, k, v, K0, K1, R, t, out);
}

// Round 14
// 84.615 us; speedup vs baseline: 1.0250x; 1.0250x over previous
//
#include <hip/hip_runtime.h>
#include <math.h>

#define NHEAD 8
#define HEAD_DIM 32
#define IMG_H 32
#define IMG_W 40
#define NPIX (IMG_H*IMG_W)
#define CMAX 160
#define CPW (CMAX/4)     // 40 candidates per wave (4 waves/block, as R33)
#define FEAT (NHEAD*HEAD_DIM)

// ===== Geometry: LOCKED bit-exact numpy-fp32 emulation =====
// R27: register-LU (explicit scalars + pivot selects, arithmetic 1:1 with
// numpy chain) -> fusable without scratch demotion. PASSED, absmax 2^-10.

__device__ __forceinline__ void np_inv3x3_reg(const float* __restrict__ M, float inv[3][3]) {
#pragma clang fp contract(off)
    float a00=M[0], a01=M[1], a02=M[2];
    float a10=M[3], a11=M[4], a12=M[5];
    float a20=M[6], a21=M[7], a22=M[8];

    // ---- kk=0: pivot search (strictly-greater update, as numpy) ----
    const float c0 = fabsf(a00), c1 = fabsf(a10), c2 = fabsf(a20);
    const bool s1 = c1 > c0;
    const float cm = s1 ? c1 : c0;
    const bool s2 = c2 > cm;
    const bool q1 = s1 && !s2;      // pivot row 1
    const bool q2 = s2;             // pivot row 2 (q1,q2 mutually exclusive)
    {   // full row swap 0 <-> p0
        const float n0 = q2 ? a20 : (q1 ? a10 : a00);
        const float n1 = q2 ? a21 : (q1 ? a11 : a01);
        const float n2 = q2 ? a22 : (q1 ? a12 : a02);
        const float m0 = q1 ? a00 : a10, m1 = q1 ? a01 : a11, m2 = q1 ? a02 : a12;
        const float r0 = q2 ? a00 : a20, r1 = q2 ? a01 : a21, r2 = q2 ? a02 : a22;
        a00=n0; a01=n1; a02=n2;
        a10=m0; a11=m1; a12=m2;
        a20=r0; a21=r1; a22=r2;
    }
    const float rp0 = 1.0f / a00;
    a10 = a10 * rp0;
    a20 = a20 * rp0;
    a11 = a11 - a10*a01;
    a12 = a12 - a10*a02;
    a21 = a21 - a20*a01;
    a22 = a22 - a20*a02;

    // ---- kk=1: pivot search over rows 1,2 ----
    const bool sB = fabsf(a21) > fabsf(a11);
    {   // full row swap 1 <-> 2 (includes factored column 0, as numpy)
        const float t0 = sB ? a20 : a10, t1 = sB ? a21 : a11, t2 = sB ? a22 : a12;
        const float u0 = sB ? a10 : a20, u1 = sB ? a11 : a21, u2 = sB ? a12 : a22;
        a10=t0; a11=t1; a12=t2;
        a20=u0; a21=u1; a22=u2;
    }
    const float rp1 = 1.0f / a11;
    a21 = a21 * rp1;
    a22 = a22 - a21*a12;
    // kk=2: pivot is row 2, no swap, no elimination.

    // ---- solve A x = e_col for col=0,1,2 (constant-trip, unrolled) ----
    #pragma unroll
    for (int col = 0; col < 3; col++) {
        float b0 = (col==0) ? 1.0f : 0.0f;
        float b1 = (col==1) ? 1.0f : 0.0f;
        float b2 = (col==2) ? 1.0f : 0.0f;
        {   // apply piv[0]
            const float w0 = q2 ? b2 : (q1 ? b1 : b0);
            const float w1 = q1 ? b0 : b1;
            const float w2 = q2 ? b0 : b2;
            b0=w0; b1=w1; b2=w2;
        }
        {   // apply piv[1]
            const float x1 = sB ? b2 : b1;
            const float x2 = sB ? b1 : b2;
            b1=x1; b2=x2;
        }
        // forward substitution (i=1:kk=0; i=2:kk=0,1)
        b1 = b1 - a10*b0;
        b2 = b2 - a20*b0;
        b2 = b2 - a21*b1;
        // back substitution (kk=2: i=0,1; kk=1: i=0; kk=0)
        b2 = b2 / a22;
        b0 = b0 - a02*b2;
        b1 = b1 - a12*b2;
        b1 = b1 / a11;
        b0 = b0 - a01*b1;
        b0 = b0 / a00;
        inv[0][col]=b0; inv[1][col]=b1; inv[2][col]=b2;
    }
}

__device__ __forceinline__ void mm3_chain(const float A[3][3], const float B[3][3], float C[3][3]) {
#pragma clang fp contract(off)
    for (int i=0;i<3;i++)
        for (int j=0;j<3;j++) {
            float acc = A[i][0]*B[0][j];
            acc = acc + A[i][1]*B[1][j];
            acc = acc + A[i][2]*B[2][j];
            C[i][j] = acc;
        }
}
__device__ __forceinline__ void mm3_fma(const float A[3][3], const float B[3][3], float C[3][3]) {
#pragma clang fp contract(off)
    for (int i=0;i<3;i++)
        for (int j=0;j<3;j++) {
            float acc = A[i][0]*B[0][j];
            acc = __builtin_fmaf(A[i][1], B[1][j], acc);
            acc = __builtin_fmaf(A[i][2], B[2][j], acc);
            C[i][j] = acc;
        }
}
__device__ __forceinline__ float einsum_row(const float Fi[3], float x, float y) {
#pragma clang fp contract(off)
    float acc = Fi[0]*x;
    acc = acc + Fi[1]*y;
    acc = acc + Fi[2]*1.0f;
    return acc;
}

// ===== R35: R33 (best, 83.4) + register-resident candidate indices =====
// R34 lesson: fewer/longer waves regressed (10 waves/CU, 80-iter chains);
// R33's 20 waves/CU was already fully resident -> revert wholesale.
// Remaining serializer (gap analysis: kernel ~25 us vs ~12 us L2-BW floor):
// per-iter chain ds_read(s_cand) -> lgkmcnt wait -> readfirstlane -> s_mul
// -> load. lgkmcnt waits are ordered, defeating cross-iter overlap of the
// LDS reads. Fix: ONE LDS read before the loop (cands = s_cand[cbase+lane],
// lanes 40-63 mirror slot 0); per unrolled iter row = __shfl(cands, i)
// with CONSTANT i -> v_readlane (register file, no lgkmcnt) -> s_mul ->
// SGPR-base load. All 40 address chains now memory-independent. Dead-slot
// semantics identical (lane 63 holds s_cand[0], e=0 masks). Everything
// else byte-identical to R33 -> absmax expected bit-identical (2^-10).

__global__ __launch_bounds__(256) void one2many_fused(
    const float* __restrict__ q, const float* __restrict__ k, const float* __restrict__ v,
    const float* __restrict__ K0, const float* __restrict__ K1,
    const float* __restrict__ R, const float* __restrict__ t,
    float* __restrict__ out)
{
#pragma clang fp contract(off)
    __shared__ int s_cand[CMAX];
    __shared__ int s_cnt;
    __shared__ float s_ax[256], s_ay[256], s_az[256], s_aw[256], s_ps[256];

    const int bx  = blockIdx.x;
    const int l   = (bx >> 3) + (bx & 7) * 160;   // XCD-contiguous bijection on [0,1280)
    const int tid = threadIdx.x;

    if (tid == 0) s_cnt = 0;

    const int w    = tid >> 6;          // wave index 0..3
    const int lane = tid & 63;          // lane -> (head = lane>>3, dims = (lane&7)*4)

    // q: each lane holds its (head,dims) slice; wave covers the full row.
    const float4 q4 = *(const float4*)(q + l*FEAT + (lane << 2));

    // ---- geometry: locked bit-exact chain, all threads, register-resident ----
    float slope, icpt; bool mode;
    {
        float i0[3][3], i1[3][3], A[3][3], B[3][3], T1[3][3], T2[3][3], Fm[3][3], Rm[3][3];
        np_inv3x3_reg(K0, i0);
        np_inv3x3_reg(K1, i1);
        for (int i=0;i<3;i++)
            for (int j=0;j<3;j++) { A[i][j] = i1[j][i]; Rm[i][j] = R[i*3+j]; }
        const float t0=t[0], t1=t[1], t2=t[2];
        B[0][0]=0.f;  B[0][1]=-t2;  B[0][2]=t1;
        B[1][0]=t2;   B[1][1]=0.f;  B[1][2]=-t0;
        B[2][0]=-t1;  B[2][1]=t0;   B[2][2]=0.f;
        mm3_chain(A,B,T1);      // noblas (swapaxes view)
        mm3_chain(T1,Rm,T2);    // T1 @ I
        mm3_fma(T2,i0,Fm);      // sgemm FMA
        const float xl = (float)(l % IMG_W);
        const float yl = (float)(l / IMG_W);
        const float la = einsum_row(Fm[0], xl, yl);
        const float lb = einsum_row(Fm[1], xl, yl);
        const float lc = einsum_row(Fm[2], xl, yl);
        mode = fabsf(lb) > fabsf(la);
        const float denom = mode ? lb : la;
        slope = (mode ? -la : -lb) / denom;
        icpt  = (-lc) / denom;
    }

    __syncthreads();   // s_cnt=0 visible

    // ---- candidate collection: identical fp32 band test ----
    for (int m = tid; m < NPIX; m += 256) {
        const float xm = (float)(m % IMG_W), ym = (float)(m / IMG_W);
        const float tin  = mode ? xm : ym;
        const float tchk = mode ? ym : xm;
        const float mu = slope * tin;
        const float cc = mu + icpt;
        const float hi = cc + 2.0f;
        const float lo = cc - 2.0f;
        if ((tchk < hi) && (tchk > lo) && m != 0) {
            int pos = atomicAdd(&s_cnt, 1);
            if (pos < CMAX) s_cand[pos] = m;
        }
    }
    __syncthreads();
    const int nc = min(s_cnt, CMAX);

    const float* kl = k + (lane << 2);
    const float* vl = v + (lane << 2);

    // ---- candidate indices -> registers: ONE LDS read for the whole loop ----
    const int cbase = w * CPW;
    // lanes 0..CPW-1 hold this wave's candidates; lanes CPW..63 hold slot 0
    const int cands = s_cand[(lane < CPW) ? (cbase + lane) : 0];

    // ---- single-pass QK+softmax+AV; one wave-uniform candidate per iter ----
    float ax = 0.f, ay = 0.f, az = 0.f, aw = 0.f, ps = 0.f;
    #pragma unroll
    for (int i = 0; i < CPW; i++) {
        const int ci   = cbase + i;
        const bool live = (ci < nc);
        // constant-lane readlane when live; lane 63 mirrors s_cand[0] when dead
        const int row  = __shfl(cands, live ? i : 63);
        const size_t off = (size_t)row * FEAT;
        const float4 kk = *(const float4*)(kl + off);   // 64 lanes -> contiguous 1024 B
        const float4 vv = *(const float4*)(vl + off);   // 64 lanes -> contiguous 1024 B
        float p = q4.x*kk.x;
        p = __builtin_fmaf(q4.y, kk.y, p);
        p = __builtin_fmaf(q4.z, kk.z, p);
        p = __builtin_fmaf(q4.w, kk.w, p);
        p += __shfl_xor(p, 1);
        p += __shfl_xor(p, 2);
        p += __shfl_xor(p, 4);              // full head-dot in all 8 lanes of the group
        const float e = live ? __expf(p * 0.17677669529663687f) : 0.0f;
        ps += e;
        ax = __builtin_fmaf(e, vv.x, ax);
        ay = __builtin_fmaf(e, vv.y, ay);
        az = __builtin_fmaf(e, vv.z, az);
        aw = __builtin_fmaf(e, vv.w, aw);
    }

    // ---- cross-wave combine (each thread owns (head,dims) partials) ----
    s_ax[tid] = ax; s_ay[tid] = ay; s_az[tid] = az; s_aw[tid] = aw; s_ps[tid] = ps;
    __syncthreads();

    if (tid < 64) {
        const float fax = ((s_ax[tid] + s_ax[tid+64]) + s_ax[tid+128]) + s_ax[tid+192];
        const float fay = ((s_ay[tid] + s_ay[tid+64]) + s_ay[tid+128]) + s_ay[tid+192];
        const float faz = ((s_az[tid] + s_az[tid+64]) + s_az[tid+128]) + s_az[tid+192];
        const float faw = ((s_aw[tid] + s_aw[tid+64]) + s_aw[tid+128]) + s_aw[tid+192];
        const float fps = ((s_ps[tid] + s_ps[tid+64]) + s_ps[tid+128]) + s_ps[tid+192];
        float4 r;
        if (nc > 0) { r.x = fax/fps; r.y = fay/fps; r.z = faz/fps; r.w = faw/fps; }
        else        { r.x = r.y = r.z = r.w = 0.0f; }
        *(float4*)(out + l*FEAT + (tid << 2)) = r;   // 64 lanes -> contiguous 1024 B
    }
}

extern "C" void kernel_launch(void* const* d_in, const int* in_sizes, int n_in,
                              void* d_out, int out_size, void* d_ws, size_t ws_size,
                              hipStream_t stream) {
    const float* q  = (const float*)d_in[0];
    const float* k  = (const float*)d_in[1];
    const float* v  = (const float*)d_in[2];
    const float* K0 = (const float*)d_in[3];
    const float* K1 = (const float*)d_in[4];
    const float* R  = (const float*)d_in[5];
    const float* t  = (const float*)d_in[6];
    float* out = (float*)d_out;
    (void)d_ws; (void)ws_size;
    one2many_fused<<<NPIX, 256, 0, stream>>>(q, k, v, K0, K1, R, t, out);
}